// Round 6
// baseline (2762.670 us; speedup 1.0000x reference)
//
#include <hip/hip_runtime.h>
#include <hip/hip_bf16.h>
#include <math.h>

#define B_    64
#define W_    255
#define S_    256
#define V_    16389
#define NLOC_ 16384
#define CLS_  16388
#define D_    512
#define H_    8
#define DH_   64
#define FF_   2048
#define L_    8
#define NTOK  (B_ * S_)

typedef __attribute__((ext_vector_type(4)))  float f32x4;
typedef __attribute__((ext_vector_type(16))) float f32x16;
typedef __attribute__((ext_vector_type(8)))  short s16x8;

__device__ inline unsigned short f2b(float f) {
  union { float f; unsigned u; } v; v.f = f;
  unsigned r = v.u + 0x7fff + ((v.u >> 16) & 1);
  return (unsigned short)(r >> 16);
}
__device__ inline void gl_lds16(const void* g, void* l) {
  __builtin_amdgcn_global_load_lds((const __attribute__((address_space(1))) unsigned int*)g,
                                   (__attribute__((address_space(3))) unsigned int*)l, 16, 0, 0);
}
// tiled layout: tile(rb,kb) 8KB contiguous; elem (r,k) at ((k>>3 & 3)*128 + r)*8 + (k&7)
__device__ inline size_t tiled_off(int row, int k, int Kb) {
  return ((size_t)(row >> 7) * Kb + (k >> 5)) * 4096 +
         ((((k >> 3) & 3) * 128 + (row & 127)) * 8) + (k & 7);
}

// ---------------- embedding + positional encoding ----------------
__global__ __launch_bounds__(256) void embed_kernel(const int* __restrict__ x,
                                                    const float* __restrict__ emb,
                                                    float* __restrict__ h) {
  const int tok = blockIdx.x;
  const int bb = tok >> 8, ss = tok & 255;
  const int idx = (ss < W_) ? x[bb * W_ + ss] : CLS_;
  const float* e = emb + (size_t)idx * D_;
  float* hp = h + (size_t)tok * D_;
  #pragma unroll
  for (int r = 0; r < 2; ++r) {
    int d = threadIdx.x + r * 256;
    float ex = exp2f(-(float)d * (13.287712379549449f / 256.0f));
    float ang = (float)ss * ex;
    float pe = (d & 1) ? cosf(ang) : sinf(ang);
    hp[d] = e[d] + pe;
  }
}

// ---------------- LayerNorm (fp32 in, bf16 out tiled or linear) ----------------
template<bool TILED>
__global__ __launch_bounds__(256) void ln_kernel(const float* __restrict__ in,
                                                 unsigned short* __restrict__ out,
                                                 const float* __restrict__ sc,
                                                 const float* __restrict__ bi) {
  const int wave = threadIdx.x >> 6;
  const int tok = blockIdx.x * 4 + wave;
  const int lane = threadIdx.x & 63;
  const float* xp = in + (size_t)tok * D_;
  float4 a = *(const float4*)(xp + lane * 4);
  float4 b = *(const float4*)(xp + 256 + lane * 4);
  float sum = a.x + a.y + a.z + a.w + b.x + b.y + b.z + b.w;
  #pragma unroll
  for (int off = 32; off; off >>= 1) sum += __shfl_xor(sum, off);
  const float mean = sum * (1.0f / D_);
  float d0 = a.x - mean, d1 = a.y - mean, d2 = a.z - mean, d3 = a.w - mean;
  float e0 = b.x - mean, e1 = b.y - mean, e2 = b.z - mean, e3 = b.w - mean;
  float ss = d0*d0 + d1*d1 + d2*d2 + d3*d3 + e0*e0 + e1*e1 + e2*e2 + e3*e3;
  #pragma unroll
  for (int off = 32; off; off >>= 1) ss += __shfl_xor(ss, off);
  const float inv = rsqrtf(ss * (1.0f / D_) + 1e-5f);
  float4 s0 = *(const float4*)(sc + lane * 4);
  float4 s1 = *(const float4*)(sc + 256 + lane * 4);
  float4 b0 = *(const float4*)(bi + lane * 4);
  float4 b1 = *(const float4*)(bi + 256 + lane * 4);
  unsigned short o[8];
  o[0] = f2b(d0 * inv * s0.x + b0.x); o[1] = f2b(d1 * inv * s0.y + b0.y);
  o[2] = f2b(d2 * inv * s0.z + b0.z); o[3] = f2b(d3 * inv * s0.w + b0.w);
  o[4] = f2b(e0 * inv * s1.x + b1.x); o[5] = f2b(e1 * inv * s1.y + b1.y);
  o[6] = f2b(e2 * inv * s1.z + b1.z); o[7] = f2b(e3 * inv * s1.w + b1.w);
  if (!TILED) {
    unsigned short* yp = out + (size_t)tok * D_;
    *(ushort4*)(yp + lane * 4)       = *(const ushort4*)&o[0];
    *(ushort4*)(yp + 256 + lane * 4) = *(const ushort4*)&o[4];
  } else {
    __shared__ unsigned short Xs[4][512];
    *(ushort4*)&Xs[wave][lane * 4]       = *(const ushort4*)&o[0];
    *(ushort4*)&Xs[wave][256 + lane * 4] = *(const ushort4*)&o[4];
    __syncthreads();
    const int c = threadIdx.x >> 2, tr = threadIdx.x & 3;
    const int tok0 = blockIdx.x * 4;
    const int rb = tok0 >> 7, r = (tok0 & 127) + tr;
    s16x8 v = *(const s16x8*)&Xs[tr][c * 8];
    *(s16x8*)(out + ((size_t)rb * 16 + (c >> 2)) * 4096 + ((c & 3) * 128 + r) * 8) = v;
  }
}

// ---------------- weight conv: W[K,N] fp32 -> tiled bf16 Wt ----------------
__global__ __launch_bounds__(256) void wconv_kernel(const float* __restrict__ W,
                                                    unsigned short* __restrict__ Wt,
                                                    int ldn, int Kb,
                                                    long in_stride, long out_stride) {
  const float* Wl = W + (size_t)blockIdx.z * in_stride;
  unsigned short* Wo = Wt + (size_t)blockIdx.z * out_stride +
                       ((size_t)blockIdx.x * Kb + blockIdx.y) * 4096;
  const int k0 = blockIdx.y * 32, n0 = blockIdx.x * 128;
  #pragma unroll
  for (int qq = 0; qq < 2; ++qq) {
    int q = qq * 256 + threadIdx.x;
    int c = q >> 7, r = q & 127;
    unsigned short o[8];
    #pragma unroll
    for (int j = 0; j < 8; ++j)
      o[j] = f2b(Wl[(size_t)(k0 + c * 8 + j) * ldn + n0 + r]);
    *(s16x8*)(Wo + (size_t)q * 8) = *(const s16x8*)o;
  }
}

// ---------------- big MFMA GEMM: 256x(NI*64) tile, 4 waves, wave = 4xNI 32x32 frags ---
// A, B both tiled (8KB tiles). LDS k-major -> conflict-free b128 frag reads.
// Epilogues staged via padded LDS (stride 264/132) for conflict-free + coalesced stores.
template<int NI, bool BIAS, bool RELU, bool RES, bool OUTBF, bool OUTTILED>
__global__ __launch_bounds__(256) void mfma_gemm_big(
    const unsigned short* __restrict__ A, long KbA,
    const unsigned short* __restrict__ Bt,
    const float* __restrict__ bias,
    float* __restrict__ Cres,
    unsigned short* __restrict__ Cbf,
    int M, int N, int K, int ldc, int kbo) {
  __shared__ __align__(16) unsigned char smem[33792];
  unsigned short* As = (unsigned short*)smem;      // 2 subs x 4096 elems
  unsigned short* Bs = As + 8192;                  // NB subs x 4096
  constexpr int NB = NI / 2;                       // 1 or 2 col sub-blocks
  const int tid = threadIdx.x;
  const int w = tid >> 6, lane = tid & 63;
  const int wm = w >> 1, wn = w & 1;
  int bx, by;
  {
    int nx = gridDim.x, ny = gridDim.y;
    int id = blockIdx.y * nx + blockIdx.x;
    if ((ny & 7) == 0) {
      int xcd = id & 7, k = id >> 3, band = ny >> 3;
      int kr = k / nx;
      by = xcd * band + kr;
      bx = k - kr * nx;
    } else { bx = blockIdx.x; by = blockIdx.y; }
  }
  const int row0 = by * 256, col0 = bx * (NI * 64);
  const int KbB = K >> 5;
  f32x16 acc[4][NI] = {};
  const int fl = lane & 31, fg2 = lane >> 5;
  for (int k0 = 0; k0 < K; k0 += 32) {
    const int kb = k0 >> 5;
    #pragma unroll
    for (int s = 0; s < 2; ++s) {
      const unsigned short* at = A + ((size_t)((row0 >> 7) + s) * KbA + kb) * 4096;
      gl_lds16(at + (size_t)tid * 8, As + s * 4096 + (size_t)tid * 8);
      gl_lds16(at + (size_t)(256 + tid) * 8, As + s * 4096 + (size_t)(256 + tid) * 8);
    }
    #pragma unroll
    for (int s = 0; s < NB; ++s) {
      const unsigned short* bt = Bt + ((size_t)((col0 >> 7) + s) * KbB + kb) * 4096;
      gl_lds16(bt + (size_t)tid * 8, Bs + s * 4096 + (size_t)tid * 8);
      gl_lds16(bt + (size_t)(256 + tid) * 8, Bs + s * 4096 + (size_t)(256 + tid) * 8);
    }
    __syncthreads();
    #pragma unroll
    for (int ks = 0; ks < 2; ++ks) {
      s16x8 af[4], bf2[NI];
      #pragma unroll
      for (int mi = 0; mi < 4; ++mi)
        af[mi] = *(const s16x8*)&As[wm * 4096 + ((ks * 2 + fg2) * 128 + mi * 32 + fl) * 8];
      #pragma unroll
      for (int ni = 0; ni < NI; ++ni) {
        int cl = wn * (NI * 32) + ni * 32 + fl;
        bf2[ni] = *(const s16x8*)&Bs[(cl >> 7) * 4096 + ((ks * 2 + fg2) * 128 + (cl & 127)) * 8];
      }
      #pragma unroll
      for (int mi = 0; mi < 4; ++mi)
        #pragma unroll
        for (int ni = 0; ni < NI; ++ni)
          acc[mi][ni] = __builtin_amdgcn_mfma_f32_32x32x16_bf16(af[mi], bf2[ni], acc[mi][ni], 0, 0, 0);
    }
    __syncthreads();
  }
  // C/D: col = wn*NI*32 + ni*32 + (lane&31); row = wm*128 + mi*32 + (rg&3)+8*(rg>>2)+4*(lane>>5)
  constexpr int C = NI * 64;
  if (OUTBF || OUTTILED) {
    unsigned short* Cs = (unsigned short*)smem;   // 64 rows x C cols, row stride 264
    #pragma unroll
    for (int rnd = 0; rnd < 4; ++rnd) {
      __syncthreads();
      if (wm == (rnd >> 1)) {
        #pragma unroll
        for (int miL = 0; miL < 2; ++miL) {
          int mi = (rnd & 1) * 2 + miL;
          #pragma unroll
          for (int ni = 0; ni < NI; ++ni) {
            int col = wn * (NI * 32) + ni * 32 + fl;
            float bv = BIAS ? bias[col0 + col] : 0.0f;
            #pragma unroll
            for (int rg = 0; rg < 16; ++rg) {
              int rl = miL * 32 + (rg & 3) + 8 * (rg >> 2) + 4 * fg2;
              float v = acc[mi][ni][rg] + bv;
              if (RELU) v = fmaxf(v, 0.0f);
              Cs[rl * 264 + col] = f2b(v);
            }
          }
        }
      }
      __syncthreads();
      if (OUTTILED) {
        #pragma unroll
        for (int i = 0; i < C / 32; ++i) {
          int q = i * 256 + tid;
          int g = q >> 6, rl = q & 63;
          int grow = row0 + rnd * 64 + rl;
          int cg = (col0 >> 3) + g;
          *(s16x8*)(Cbf + ((size_t)(grow >> 7) * kbo + (cg >> 2)) * 4096 +
                    ((cg & 3) * 128 + (grow & 127)) * 8) =
              *(const s16x8*)&Cs[rl * 264 + g * 8];
        }
      } else {
        #pragma unroll
        for (int i = 0; i < C / 32; ++i) {
          int q = i * 256 + tid;
          int row = q / (C / 8), cc = q & (C / 8 - 1);
          *(s16x8*)(Cbf + (size_t)(row0 + rnd * 64 + row) * ldc + col0 + cc * 8) =
              *(const s16x8*)&Cs[row * 264 + cc * 8];
        }
      }
    }
  } else {
    float* Csf = (float*)smem;   // 64 x 128 f32, row stride 132
    #pragma unroll
    for (int rnd = 0; rnd < 4; ++rnd) {
      __syncthreads();
      if (wm == (rnd >> 1)) {
        #pragma unroll
        for (int miL = 0; miL < 2; ++miL) {
          int mi = (rnd & 1) * 2 + miL;
          #pragma unroll
          for (int ni = 0; ni < NI; ++ni) {
            int col = wn * (NI * 32) + ni * 32 + fl;
            float bv = BIAS ? bias[col0 + col] : 0.0f;
            #pragma unroll
            for (int rg = 0; rg < 16; ++rg) {
              int rl = miL * 32 + (rg & 3) + 8 * (rg >> 2) + 4 * fg2;
              float v = acc[mi][ni][rg] + bv;
              if (RELU) v = fmaxf(v, 0.0f);
              Csf[rl * 132 + col] = v;
            }
          }
        }
      }
      __syncthreads();
      #pragma unroll
      for (int i = 0; i < 8; ++i) {
        int q = i * 256 + tid;
        int rl = q >> 5, cc = q & 31;
        int grow = row0 + rnd * 64 + rl;
        float4 v = *(const float4*)&Csf[rl * 132 + cc * 4];
        float* gp = Cres + (size_t)grow * ldc + col0 + cc * 4;
        if (RES) {
          float4 hv = *(const float4*)gp;
          v.x += hv.x; v.y += hv.y; v.z += hv.z; v.w += hv.w;
        }
        *(float4*)gp = v;
      }
    }
  }
}

// ---------------- small 128x128 MFMA GEMM (head only: M=64, fp32 out, B tiled) --------
__global__ __launch_bounds__(256) void head_gemm(
    const unsigned short* __restrict__ A, long lda,
    const unsigned short* __restrict__ Bt,
    float* __restrict__ Cres,
    int M, int N, int K, int ldc) {
  __shared__ __align__(16) unsigned char smem[16384];
  unsigned short* As = (unsigned short*)smem;
  unsigned short* Bs = As + 128 * 32;
  const int tid = threadIdx.x;
  const int w = tid >> 6, lane = tid & 63;
  const int wm = w >> 1, wn = w & 1;
  const int row0 = blockIdx.y * 128, col0 = blockIdx.x * 128;
  const int KbB = K >> 5;
  f32x16 acc[2][2] = {};
  const int fl = lane & 31, fg2 = lane >> 5;
  const int sc8 = w * 8;
  for (int k0 = 0; k0 < K; k0 += 32) {
    #pragma unroll
    for (int i = 0; i < 2; ++i) {
      int r = i * 64 + lane;
      int ar = row0 + r; if (ar >= M) ar = M - 1;
      gl_lds16(A + (size_t)ar * lda + k0 + sc8, As + (w * 2 + i) * 512);
    }
    {
      const unsigned short* bt = Bt + ((size_t)(col0 >> 7) * KbB + (k0 >> 5)) * 4096;
      gl_lds16(bt + (size_t)tid * 8, Bs + (size_t)tid * 8);
      gl_lds16(bt + (size_t)(256 + tid) * 8, Bs + (size_t)(256 + tid) * 8);
    }
    __syncthreads();
    #pragma unroll
    for (int ks = 0; ks < 2; ++ks) {
      s16x8 af[2], bf2[2];
      #pragma unroll
      for (int mi = 0; mi < 2; ++mi)
        af[mi] = *(const s16x8*)&As[((ks * 2 + fg2) * 128 + wm * 64 + mi * 32 + fl) * 8];
      #pragma unroll
      for (int ni = 0; ni < 2; ++ni)
        bf2[ni] = *(const s16x8*)&Bs[((ks * 2 + fg2) * 128 + wn * 64 + ni * 32 + fl) * 8];
      #pragma unroll
      for (int mi = 0; mi < 2; ++mi)
        #pragma unroll
        for (int ni = 0; ni < 2; ++ni)
          acc[mi][ni] = __builtin_amdgcn_mfma_f32_32x32x16_bf16(af[mi], bf2[ni], acc[mi][ni], 0, 0, 0);
    }
    __syncthreads();
  }
  float* Csf = (float*)smem;
  #pragma unroll
  for (int q = 0; q < 4; ++q) {
    __syncthreads();
    if (wm == (q >> 1)) {
      const int mi = q & 1;
      #pragma unroll
      for (int ni = 0; ni < 2; ++ni) {
        int col = wn * 64 + ni * 32 + fl;
        #pragma unroll
        for (int rg = 0; rg < 16; ++rg) {
          int rl = (rg & 3) + 8 * (rg >> 2) + 4 * fg2;
          Csf[rl * 128 + col] = acc[mi][ni][rg];
        }
      }
    }
    __syncthreads();
    #pragma unroll
    for (int i = 0; i < 4; ++i) {
      int chunk = i * 256 + tid;
      int row = chunk >> 5, cc = chunk & 31;
      int grow = row0 + q * 32 + row;
      if (grow < M) {
        float4 v = *(const float4*)&Csf[row * 128 + cc * 4];
        *(float4*)(Cres + (size_t)grow * ldc + col0 + cc * 4) = v;
      }
    }
  }
}

// ---------------- V transpose: qkvb V-cols -> vtg[(b*H+h)][d][j] (bf16) ----------------
__global__ __launch_bounds__(256) void vt_kernel(const unsigned short* __restrict__ qkvb,
                                                 unsigned short* __restrict__ vtg) {
  const int bh = blockIdx.x;
  const int jt = blockIdx.y;
  const int bb = bh >> 3, hh = bh & 7;
  __shared__ unsigned short t[64][72];
  const int r = threadIdx.x >> 2;
  const int c = (threadIdx.x & 3) * 16;
  const unsigned short* src = qkvb + (size_t)(bb * 256 + jt * 64 + r) * 1536 + 1024 + hh * 64 + c;
  *(s16x8*)&t[r][c]     = *(const s16x8*)src;
  *(s16x8*)&t[r][c + 8] = *(const s16x8*)(src + 8);
  __syncthreads();
  unsigned short tmp[16];
  #pragma unroll
  for (int i = 0; i < 16; ++i) tmp[i] = t[c + i][r];
  unsigned short* dst = vtg + ((size_t)bh * 64 + r) * 256 + jt * 64 + c;
  *(s16x8*)dst       = *(const s16x8*)&tmp[0];
  *(s16x8*)(dst + 8) = *(const s16x8*)&tmp[8];
}

// ---------------- fused MFMA attention: one block per (b,h); obuf written TILED ------
__global__ __launch_bounds__(256) void attn_mfma(const unsigned short* __restrict__ qkvb,
                                                 const unsigned short* __restrict__ vtg,
                                                 unsigned short* __restrict__ obuf) {
  const int bh = blockIdx.x;
  const int bb = bh >> 3, hh = bh & 7;
  const int tid = threadIdx.x, w = tid >> 6, lane = tid & 63;
  __shared__ unsigned short Pl[4][16][264];
  const int fr = lane & 15, fg = lane >> 4;
  const unsigned short* qbase = qkvb + (size_t)bb * 256 * 1536 + hh * 64;
  const unsigned short* kbase = qbase + 512;
  const unsigned short* vb = vtg + (size_t)bh * 64 * 256;

  for (int s = w; s < 16; s += 4) {
    const int q0 = s * 16;
    f32x4 sacc[16] = {};
    s16x8 aq[2];
    #pragma unroll
    for (int kk = 0; kk < 2; ++kk)
      aq[kk] = *(const s16x8*)(qbase + (size_t)(q0 + fr) * 1536 + kk * 32 + fg * 8);
    #pragma unroll
    for (int ni = 0; ni < 16; ++ni) {
      #pragma unroll
      for (int kk = 0; kk < 2; ++kk) {
        s16x8 bk = *(const s16x8*)(kbase + (size_t)(ni * 16 + fr) * 1536 + kk * 32 + fg * 8);
        sacc[ni] = __builtin_amdgcn_mfma_f32_16x16x32_bf16(aq[kk], bk, sacc[ni], 0, 0, 0);
      }
    }
    #pragma unroll
    for (int rr = 0; rr < 4; ++rr) {
      float mx = -1e30f;
      #pragma unroll
      for (int ni = 0; ni < 16; ++ni) mx = fmaxf(mx, sacc[ni][rr]);
      #pragma unroll
      for (int off = 1; off <= 8; off <<= 1) mx = fmaxf(mx, __shfl_xor(mx, off));
      float sum = 0.0f;
      #pragma unroll
      for (int ni = 0; ni < 16; ++ni) {
        float e = __expf((sacc[ni][rr] - mx) * 0.125f);
        sacc[ni][rr] = e; sum += e;
      }
      #pragma unroll
      for (int off = 1; off <= 8; off <<= 1) sum += __shfl_xor(sum, off);
      float inv = 1.0f / sum;
      #pragma unroll
      for (int ni = 0; ni < 16; ++ni) sacc[ni][rr] *= inv;
    }
    #pragma unroll
    for (int ni = 0; ni < 16; ++ni)
      #pragma unroll
      for (int rr = 0; rr < 4; ++rr)
        Pl[w][fg * 4 + rr][ni * 16 + fr] = f2b(sacc[ni][rr]);
    f32x4 oacc[4] = {};
    #pragma unroll
    for (int kk = 0; kk < 8; ++kk) {
      s16x8 ap = *(const s16x8*)&Pl[w][fr][kk * 32 + fg * 8];
      #pragma unroll
      for (int ni = 0; ni < 4; ++ni) {
        s16x8 bv = *(const s16x8*)(vb + (size_t)(ni * 16 + fr) * 256 + kk * 32 + fg * 8);
        oacc[ni] = __builtin_amdgcn_mfma_f32_16x16x32_bf16(ap, bv, oacc[ni], 0, 0, 0);
      }
    }
    #pragma unroll
    for (int ni = 0; ni < 4; ++ni)
      #pragma unroll
      for (int rr = 0; rr < 4; ++rr) {
        int row = bb * 256 + q0 + fg * 4 + rr;
        int k = hh * 64 + ni * 16 + fr;
        obuf[tiled_off(row, k, 16)] = f2b(oacc[ni][rr]);
      }
  }
}

extern "C" void kernel_launch(void* const* d_in, const int* in_sizes, int n_in,
                              void* d_out, int out_size, void* d_ws, size_t ws_size,
                              hipStream_t stream) {
  const int*   x      = (const int*)  d_in[0];
  const float* emb    = (const float*)d_in[1];
  const float* qkv_w  = (const float*)d_in[2];
  const float* qkv_b  = (const float*)d_in[3];
  const float* out_w  = (const float*)d_in[4];
  const float* out_b  = (const float*)d_in[5];
  const float* ln1_s  = (const float*)d_in[6];
  const float* ln1_b  = (const float*)d_in[7];
  const float* ln2_s  = (const float*)d_in[8];
  const float* ln2_b  = (const float*)d_in[9];
  const float* ff1_w  = (const float*)d_in[10];
  const float* ff1_b  = (const float*)d_in[11];
  const float* ff2_w  = (const float*)d_in[12];
  const float* ff2_b  = (const float*)d_in[13];
  const float* fn_s   = (const float*)d_in[14];
  const float* fn_b   = (const float*)d_in[15];
  const float* head_w = (const float*)d_in[16];
  float* out = (float*)d_out;

  char* p = (char*)d_ws;
  float* h = (float*)p;                      p += (size_t)NTOK * D_ * 4;
  unsigned short* x2b = (unsigned short*)p;  p += (size_t)NTOK * D_ * 2;
  unsigned short* qkvb = (unsigned short*)p; p += (size_t)NTOK * 3 * D_ * 2;
  unsigned short* vtg = (unsigned short*)p;  p += (size_t)B_ * H_ * DH_ * S_ * 2;
  unsigned short* obuf = (unsigned short*)p; p += (size_t)NTOK * D_ * 2;
  unsigned short* wt_qkv = (unsigned short*)p; p += (size_t)L_ * D_ * 3 * D_ * 2;
  unsigned short* wt_out = (unsigned short*)p; p += (size_t)L_ * D_ * D_ * 2;
  unsigned short* wt_ff1 = (unsigned short*)p; p += (size_t)L_ * D_ * FF_ * 2;
  unsigned short* wt_ff2 = (unsigned short*)p; p += (size_t)FF_ * D_ * L_ * 2;
  unsigned short* wth = (unsigned short*)p;    p += (size_t)NLOC_ * D_ * 2;
  unsigned short* ffmid = qkvb;  // alias: qkvb+vtg+obuf (~80.8 MB) >= 64 MB, dead during FF

  embed_kernel<<<NTOK, 256, 0, stream>>>(x, emb, h);
  wconv_kernel<<<dim3(3 * D_ / 128, D_ / 32, L_), 256, 0, stream>>>(
      qkv_w, wt_qkv, 3 * D_, D_ / 32, (long)D_ * 3 * D_, (long)D_ * 3 * D_);
  wconv_kernel<<<dim3(D_ / 128, D_ / 32, L_), 256, 0, stream>>>(
      out_w, wt_out, D_, D_ / 32, (long)D_ * D_, (long)D_ * D_);
  wconv_kernel<<<dim3(FF_ / 128, D_ / 32, L_), 256, 0, stream>>>(
      ff1_w, wt_ff1, FF_, D_ / 32, (long)D_ * FF_, (long)D_ * FF_);
  wconv_kernel<<<dim3(D_ / 128, FF_ / 32, L_), 256, 0, stream>>>(
      ff2_w, wt_ff2, D_, FF_ / 32, (long)FF_ * D_, (long)FF_ * D_);
  wconv_kernel<<<dim3(NLOC_ / 128, D_ / 32, 1), 256, 0, stream>>>(
      head_w, wth, V_, D_ / 32, 0, 0);

  for (int l = 0; l < L_; ++l) {
    ln_kernel<true><<<NTOK / 4, 256, 0, stream>>>(h, x2b, ln1_s + l * D_, ln1_b + l * D_);
    // qkv: 256x256 tiles, A=x2b tiled (Kb=16), out=qkvb linear bf16
    mfma_gemm_big<4, true, false, false, true, false><<<dim3(3 * D_ / 256, NTOK / 256), 256, 0, stream>>>(
        x2b, 16, wt_qkv + (size_t)l * D_ * 3 * D_, qkv_b + (size_t)l * 3 * D_, nullptr, qkvb,
        NTOK, 3 * D_, D_, 3 * D_, 0);
    vt_kernel<<<dim3(B_ * H_, 4), 256, 0, stream>>>(qkvb, vtg);
    attn_mfma<<<B_ * H_, 256, 0, stream>>>(qkvb, vtg, obuf);
    // out-proj: 256x128 tiles, A=obuf tiled (Kb=16), fp32 residual into h
    mfma_gemm_big<2, true, false, true, false, false><<<dim3(D_ / 128, NTOK / 256), 256, 0, stream>>>(
        obuf, 16, wt_out + (size_t)l * D_ * D_, out_b + (size_t)l * D_, h, nullptr,
        NTOK, D_, D_, D_, 0);
    ln_kernel<true><<<NTOK / 4, 256, 0, stream>>>(h, x2b, ln2_s + l * D_, ln2_b + l * D_);
    // ff1: 256x256 tiles, A=x2b tiled (Kb=16), out=ffmid TILED bf16 (Kb=64)
    mfma_gemm_big<4, true, true, false, false, true><<<dim3(FF_ / 256, NTOK / 256), 256, 0, stream>>>(
        x2b, 16, wt_ff1 + (size_t)l * D_ * FF_, ff1_b + (size_t)l * FF_, nullptr, ffmid,
        NTOK, FF_, D_, FF_, 64);
    // ff2: 256x128 tiles, A=ffmid tiled (Kb=64), fp32 residual into h
    mfma_gemm_big<2, true, false, true, false, false><<<dim3(D_ / 128, NTOK / 256), 256, 0, stream>>>(
        ffmid, 64, wt_ff2 + (size_t)l * FF_ * D_, ff2_b + (size_t)l * D_, h, nullptr,
        NTOK, D_, FF_, D_, 0);
  }
  ln_kernel<false><<<NTOK / 4, 256, 0, stream>>>(h, x2b, fn_s, fn_b);
  head_gemm<<<dim3(NLOC_ / 128, 1), 256, 0, stream>>>(
      x2b + (size_t)(S_ - 1) * D_, (long)S_ * D_, wth, out, B_, NLOC_, D_, NLOC_);
}

// Round 7
// 2118.490 us; speedup vs baseline: 1.3041x; 1.3041x over previous
//
#include <hip/hip_runtime.h>
#include <hip/hip_bf16.h>
#include <math.h>

#define B_    64
#define W_    255
#define S_    256
#define V_    16389
#define NLOC_ 16384
#define CLS_  16388
#define D_    512
#define H_    8
#define DH_   64
#define FF_   2048
#define L_    8
#define NTOK  (B_ * S_)

typedef __attribute__((ext_vector_type(4)))  float f32x4;
typedef __attribute__((ext_vector_type(16))) float f32x16;
typedef __attribute__((ext_vector_type(8)))  short s16x8;

__device__ inline unsigned short f2b(float f) {
  union { float f; unsigned u; } v; v.f = f;
  unsigned r = v.u + 0x7fff + ((v.u >> 16) & 1);
  return (unsigned short)(r >> 16);
}
__device__ inline void gl_lds16(const void* g, void* l) {
  __builtin_amdgcn_global_load_lds((const __attribute__((address_space(1))) unsigned int*)g,
                                   (__attribute__((address_space(3))) unsigned int*)l, 16, 0, 0);
}
// tiled layout: tile(rb,kb) 8KB contiguous; elem (r,k) at ((k>>3 & 3)*128 + r)*8 + (k&7)
__device__ inline size_t tiled_off(int row, int k, int Kb) {
  return ((size_t)(row >> 7) * Kb + (k >> 5)) * 4096 +
         ((((k >> 3) & 3) * 128 + (row & 127)) * 8) + (k & 7);
}

// ---------------- embedding + positional encoding ----------------
__global__ __launch_bounds__(256) void embed_kernel(const int* __restrict__ x,
                                                    const float* __restrict__ emb,
                                                    float* __restrict__ h) {
  const int tok = blockIdx.x;
  const int bb = tok >> 8, ss = tok & 255;
  const int idx = (ss < W_) ? x[bb * W_ + ss] : CLS_;
  const float* e = emb + (size_t)idx * D_;
  float* hp = h + (size_t)tok * D_;
  #pragma unroll
  for (int r = 0; r < 2; ++r) {
    int d = threadIdx.x + r * 256;
    float ex = exp2f(-(float)d * (13.287712379549449f / 256.0f));
    float ang = (float)ss * ex;
    float pe = (d & 1) ? cosf(ang) : sinf(ang);
    hp[d] = e[d] + pe;
  }
}

// ---------------- LayerNorm (fp32 in, bf16 out tiled or linear) ----------------
template<bool TILED>
__global__ __launch_bounds__(256) void ln_kernel(const float* __restrict__ in,
                                                 unsigned short* __restrict__ out,
                                                 const float* __restrict__ sc,
                                                 const float* __restrict__ bi) {
  const int wave = threadIdx.x >> 6;
  const int tok = blockIdx.x * 4 + wave;
  const int lane = threadIdx.x & 63;
  const float* xp = in + (size_t)tok * D_;
  float4 a = *(const float4*)(xp + lane * 4);
  float4 b = *(const float4*)(xp + 256 + lane * 4);
  float sum = a.x + a.y + a.z + a.w + b.x + b.y + b.z + b.w;
  #pragma unroll
  for (int off = 32; off; off >>= 1) sum += __shfl_xor(sum, off);
  const float mean = sum * (1.0f / D_);
  float d0 = a.x - mean, d1 = a.y - mean, d2 = a.z - mean, d3 = a.w - mean;
  float e0 = b.x - mean, e1 = b.y - mean, e2 = b.z - mean, e3 = b.w - mean;
  float ss = d0*d0 + d1*d1 + d2*d2 + d3*d3 + e0*e0 + e1*e1 + e2*e2 + e3*e3;
  #pragma unroll
  for (int off = 32; off; off >>= 1) ss += __shfl_xor(ss, off);
  const float inv = rsqrtf(ss * (1.0f / D_) + 1e-5f);
  float4 s0 = *(const float4*)(sc + lane * 4);
  float4 s1 = *(const float4*)(sc + 256 + lane * 4);
  float4 b0 = *(const float4*)(bi + lane * 4);
  float4 b1 = *(const float4*)(bi + 256 + lane * 4);
  unsigned short o[8];
  o[0] = f2b(d0 * inv * s0.x + b0.x); o[1] = f2b(d1 * inv * s0.y + b0.y);
  o[2] = f2b(d2 * inv * s0.z + b0.z); o[3] = f2b(d3 * inv * s0.w + b0.w);
  o[4] = f2b(e0 * inv * s1.x + b1.x); o[5] = f2b(e1 * inv * s1.y + b1.y);
  o[6] = f2b(e2 * inv * s1.z + b1.z); o[7] = f2b(e3 * inv * s1.w + b1.w);
  if (!TILED) {
    unsigned short* yp = out + (size_t)tok * D_;
    *(ushort4*)(yp + lane * 4)       = *(const ushort4*)&o[0];
    *(ushort4*)(yp + 256 + lane * 4) = *(const ushort4*)&o[4];
  } else {
    __shared__ unsigned short Xs[4][512];
    *(ushort4*)&Xs[wave][lane * 4]       = *(const ushort4*)&o[0];
    *(ushort4*)&Xs[wave][256 + lane * 4] = *(const ushort4*)&o[4];
    __syncthreads();
    const int c = threadIdx.x >> 2, tr = threadIdx.x & 3;
    const int tok0 = blockIdx.x * 4;
    const int rb = tok0 >> 7, r = (tok0 & 127) + tr;
    s16x8 v = *(const s16x8*)&Xs[tr][c * 8];
    *(s16x8*)(out + ((size_t)rb * 16 + (c >> 2)) * 4096 + ((c & 3) * 128 + r) * 8) = v;
  }
}

// ---------------- weight conv: W[K,N] fp32 -> tiled bf16 Wt ----------------
__global__ __launch_bounds__(256) void wconv_kernel(const float* __restrict__ W,
                                                    unsigned short* __restrict__ Wt,
                                                    int ldn, int Kb,
                                                    long in_stride, long out_stride) {
  const float* Wl = W + (size_t)blockIdx.z * in_stride;
  unsigned short* Wo = Wt + (size_t)blockIdx.z * out_stride +
                       ((size_t)blockIdx.x * Kb + blockIdx.y) * 4096;
  const int k0 = blockIdx.y * 32, n0 = blockIdx.x * 128;
  #pragma unroll
  for (int qq = 0; qq < 2; ++qq) {
    int q = qq * 256 + threadIdx.x;
    int c = q >> 7, r = q & 127;
    unsigned short o[8];
    #pragma unroll
    for (int j = 0; j < 8; ++j)
      o[j] = f2b(Wl[(size_t)(k0 + c * 8 + j) * ldn + n0 + r]);
    *(s16x8*)(Wo + (size_t)q * 8) = *(const s16x8*)o;
  }
}

// ---------------- MFMA GEMM: 128x128 tile, BK=64, 4 waves (2x2), 2x2 32x32x16 frags --
// A, B tiled (8KB tiles) -> linear coalesced staging; k-major LDS -> conflict-free
// b128 frag reads. XCD-band swizzle. Padded-LDS epilogues for coalesced 16B stores.
template<bool BIAS, bool RELU, bool RES, bool OUTBF, bool OUTTILED>
__global__ __launch_bounds__(256) void mfma_gemm(
    const unsigned short* __restrict__ A, long KbA,
    const unsigned short* __restrict__ Bt,
    const float* __restrict__ bias,
    float* __restrict__ Cres,
    unsigned short* __restrict__ Cbf,
    int M, int N, int K, int ldc, int kbo) {
  __shared__ __align__(16) unsigned char smem[32768];
  unsigned short* As = (unsigned short*)smem;   // 2 subs x (4 chunk-cols x 128 x 8)
  unsigned short* Bs = As + 8192;
  const int tid = threadIdx.x;
  const int w = tid >> 6, lane = tid & 63;
  const int wm = w >> 1, wn = w & 1;
  int bx, by;
  {
    int nx = gridDim.x, ny = gridDim.y;
    int id = blockIdx.y * nx + blockIdx.x;
    if ((ny & 7) == 0) {
      int xcd = id & 7, k = id >> 3, band = ny >> 3;
      int kr = k / nx;
      by = xcd * band + kr;
      bx = k - kr * nx;
    } else { bx = blockIdx.x; by = blockIdx.y; }
  }
  const int row0 = by * 128, col0 = bx * 128;
  const int KbB = K >> 5;
  f32x16 acc[2][2] = {};
  const int fl = lane & 31, fg2 = lane >> 5;
  for (int k0 = 0; k0 < K; k0 += 64) {
    const int kb = k0 >> 5;
    #pragma unroll
    for (int s2 = 0; s2 < 2; ++s2) {
      const unsigned short* at = A + ((size_t)(row0 >> 7) * KbA + kb + s2) * 4096;
      gl_lds16(at + (size_t)tid * 8, As + s2 * 4096 + (size_t)tid * 8);
      gl_lds16(at + (size_t)(256 + tid) * 8, As + s2 * 4096 + (size_t)(256 + tid) * 8);
      const unsigned short* bt = Bt + ((size_t)(col0 >> 7) * KbB + kb + s2) * 4096;
      gl_lds16(bt + (size_t)tid * 8, Bs + s2 * 4096 + (size_t)tid * 8);
      gl_lds16(bt + (size_t)(256 + tid) * 8, Bs + s2 * 4096 + (size_t)(256 + tid) * 8);
    }
    __syncthreads();
    #pragma unroll
    for (int ks = 0; ks < 4; ++ks) {
      const int sub = ks >> 1, kk = ks & 1;
      s16x8 af[2], bf2[2];
      #pragma unroll
      for (int mi = 0; mi < 2; ++mi)
        af[mi] = *(const s16x8*)&As[sub * 4096 + ((kk * 2 + fg2) * 128 + wm * 64 + mi * 32 + fl) * 8];
      #pragma unroll
      for (int ni = 0; ni < 2; ++ni)
        bf2[ni] = *(const s16x8*)&Bs[sub * 4096 + ((kk * 2 + fg2) * 128 + wn * 64 + ni * 32 + fl) * 8];
      #pragma unroll
      for (int mi = 0; mi < 2; ++mi)
        #pragma unroll
        for (int ni = 0; ni < 2; ++ni)
          acc[mi][ni] = __builtin_amdgcn_mfma_f32_32x32x16_bf16(af[mi], bf2[ni], acc[mi][ni], 0, 0, 0);
    }
    __syncthreads();
  }
  // C/D: col = wn*64+ni*32+(lane&31), row = wm*64+mi*32+(rg&3)+8*(rg>>2)+4*(lane>>5)
  if (OUTBF || OUTTILED) {
    unsigned short* Cs = (unsigned short*)smem;   // 64 rows x stride 136
    #pragma unroll
    for (int half = 0; half < 2; ++half) {
      __syncthreads();
      if (wm == half) {
        #pragma unroll
        for (int mi = 0; mi < 2; ++mi)
          #pragma unroll
          for (int ni = 0; ni < 2; ++ni) {
            int col = wn * 64 + ni * 32 + fl;
            float bv = BIAS ? bias[col0 + col] : 0.0f;
            #pragma unroll
            for (int rg = 0; rg < 16; ++rg) {
              int rl = mi * 32 + (rg & 3) + 8 * (rg >> 2) + 4 * fg2;
              float v = acc[mi][ni][rg] + bv;
              if (RELU) v = fmaxf(v, 0.0f);
              Cs[rl * 136 + col] = f2b(v);
            }
          }
      }
      __syncthreads();
      if (OUTTILED) {
        #pragma unroll
        for (int i = 0; i < 4; ++i) {
          int q = i * 256 + tid;
          int g = q >> 6, rl = q & 63;
          int grow = row0 + half * 64 + rl;
          int cg = (col0 >> 3) + g;
          *(s16x8*)(Cbf + ((size_t)(grow >> 7) * kbo + (cg >> 2)) * 4096 +
                    ((cg & 3) * 128 + (grow & 127)) * 8) =
              *(const s16x8*)&Cs[rl * 136 + g * 8];
        }
      } else {
        #pragma unroll
        for (int i = 0; i < 4; ++i) {
          int chunk = i * 256 + tid;
          int row = chunk >> 4, cc = chunk & 15;
          *(s16x8*)(Cbf + (size_t)(row0 + half * 64 + row) * ldc + col0 + cc * 8) =
              *(const s16x8*)&Cs[row * 136 + cc * 8];
        }
      }
    }
  } else {
    float* Csf = (float*)smem;   // 32 rows x stride 132 f32
    #pragma unroll
    for (int q = 0; q < 4; ++q) {
      __syncthreads();
      if (wm == (q >> 1)) {
        const int mi = q & 1;
        #pragma unroll
        for (int ni = 0; ni < 2; ++ni) {
          int col = wn * 64 + ni * 32 + fl;
          float bv = BIAS ? bias[col0 + col] : 0.0f;
          #pragma unroll
          for (int rg = 0; rg < 16; ++rg) {
            int rl = (rg & 3) + 8 * (rg >> 2) + 4 * fg2;
            float v = acc[mi][ni][rg] + bv;
            if (RELU) v = fmaxf(v, 0.0f);
            Csf[rl * 132 + col] = v;
          }
        }
      }
      __syncthreads();
      #pragma unroll
      for (int i = 0; i < 4; ++i) {
        int chunk = i * 256 + tid;
        int row = chunk >> 5, cc = chunk & 31;
        int grow = row0 + q * 32 + row;
        float4 v = *(const float4*)&Csf[row * 132 + cc * 4];
        float* gp = Cres + (size_t)grow * ldc + col0 + cc * 4;
        if (RES) {
          float4 hv = *(const float4*)gp;
          v.x += hv.x; v.y += hv.y; v.z += hv.z; v.w += hv.w;
        }
        *(float4*)gp = v;
      }
    }
  }
}

// ---------------- head GEMM (M=64, A linear w/ row clamp, B tiled, fp32 out) ----------
__global__ __launch_bounds__(256) void head_gemm(
    const unsigned short* __restrict__ A, long lda,
    const unsigned short* __restrict__ Bt,
    float* __restrict__ Cres,
    int M, int N, int K, int ldc) {
  __shared__ __align__(16) unsigned char smem[16384];
  unsigned short* As = (unsigned short*)smem;
  unsigned short* Bs = As + 128 * 32;
  const int tid = threadIdx.x;
  const int w = tid >> 6, lane = tid & 63;
  const int wm = w >> 1, wn = w & 1;
  const int row0 = blockIdx.y * 128, col0 = blockIdx.x * 128;
  const int KbB = K >> 5;
  f32x16 acc[2][2] = {};
  const int fl = lane & 31, fg2 = lane >> 5;
  const int sc8 = w * 8;
  for (int k0 = 0; k0 < K; k0 += 32) {
    #pragma unroll
    for (int i = 0; i < 2; ++i) {
      int r = i * 64 + lane;
      int ar = row0 + r; if (ar >= M) ar = M - 1;
      gl_lds16(A + (size_t)ar * lda + k0 + sc8, As + (w * 2 + i) * 512);
    }
    {
      const unsigned short* bt = Bt + ((size_t)(col0 >> 7) * KbB + (k0 >> 5)) * 4096;
      gl_lds16(bt + (size_t)tid * 8, Bs + (size_t)tid * 8);
      gl_lds16(bt + (size_t)(256 + tid) * 8, Bs + (size_t)(256 + tid) * 8);
    }
    __syncthreads();
    #pragma unroll
    for (int ks = 0; ks < 2; ++ks) {
      s16x8 af[2], bf2[2];
      #pragma unroll
      for (int mi = 0; mi < 2; ++mi)
        af[mi] = *(const s16x8*)&As[((ks * 2 + fg2) * 128 + wm * 64 + mi * 32 + fl) * 8];
      #pragma unroll
      for (int ni = 0; ni < 2; ++ni)
        bf2[ni] = *(const s16x8*)&Bs[((ks * 2 + fg2) * 128 + wn * 64 + ni * 32 + fl) * 8];
      #pragma unroll
      for (int mi = 0; mi < 2; ++mi)
        #pragma unroll
        for (int ni = 0; ni < 2; ++ni)
          acc[mi][ni] = __builtin_amdgcn_mfma_f32_32x32x16_bf16(af[mi], bf2[ni], acc[mi][ni], 0, 0, 0);
    }
    __syncthreads();
  }
  float* Csf = (float*)smem;
  #pragma unroll
  for (int q = 0; q < 4; ++q) {
    __syncthreads();
    if (wm == (q >> 1)) {
      const int mi = q & 1;
      #pragma unroll
      for (int ni = 0; ni < 2; ++ni) {
        int col = wn * 64 + ni * 32 + fl;
        #pragma unroll
        for (int rg = 0; rg < 16; ++rg) {
          int rl = (rg & 3) + 8 * (rg >> 2) + 4 * fg2;
          Csf[rl * 128 + col] = acc[mi][ni][rg];
        }
      }
    }
    __syncthreads();
    #pragma unroll
    for (int i = 0; i < 4; ++i) {
      int chunk = i * 256 + tid;
      int row = chunk >> 5, cc = chunk & 31;
      int grow = row0 + q * 32 + row;
      if (grow < M) {
        float4 v = *(const float4*)&Csf[row * 128 + cc * 4];
        *(float4*)(Cres + (size_t)grow * ldc + col0 + cc * 4) = v;
      }
    }
  }
}

// ---------------- fused MFMA attention: one block per (b,h) ----------------
// V transposed into LDS (swizzled) at block start; K/Q read from global (K is L1-hot);
// P strip round-trips per-wave swizzled LDS; obuf written tiled.
__global__ __launch_bounds__(256) void attn_mfma(const unsigned short* __restrict__ qkvb,
                                                 unsigned short* __restrict__ obuf) {
  const int bh = blockIdx.x;
  const int bb = bh >> 3, hh = bh & 7;
  const int tid = threadIdx.x, w = tid >> 6, lane = tid & 63;
  // swizzled elem (r, k): r*256 + ((k>>3)^(r&7))*8 + (k&7)
  __shared__ unsigned short Vt[64 * 256];        // (d, j)
  __shared__ unsigned short Pl[4][16 * 256];     // per-wave (q, j)
  const int fr = lane & 15, fg = lane >> 4;
  const unsigned short* qbase = qkvb + (size_t)bb * 256 * 1536 + hh * 64;
  const unsigned short* kbase = qbase + 512;
  const unsigned short* vbase = qbase + 1024;

  // ---- stage V^T into LDS (one-time transpose) ----
  #pragma unroll
  for (int i = 0; i < 8; ++i) {
    int pair = i * 256 + tid;          // j = pair>>3 (0..255), c = pair&7
    int j = pair >> 3, c = pair & 7;
    s16x8 v = *(const s16x8*)(vbase + (size_t)j * 1536 + c * 8);
    #pragma unroll
    for (int e = 0; e < 8; ++e) {
      int d = c * 8 + e;
      Vt[d * 256 + (((j >> 3) ^ (d & 7)) << 3) + (j & 7)] = ((unsigned short*)&v)[e];
    }
  }
  __syncthreads();

  for (int s = w; s < 16; s += 4) {
    const int q0 = s * 16;
    // ---- S = Q K^T (strip: 16 q x 256 keys) ----
    f32x4 sacc[16] = {};
    s16x8 aq[2];
    #pragma unroll
    for (int kk = 0; kk < 2; ++kk)
      aq[kk] = *(const s16x8*)(qbase + (size_t)(q0 + fr) * 1536 + kk * 32 + fg * 8);
    #pragma unroll
    for (int ni = 0; ni < 16; ++ni) {
      #pragma unroll
      for (int kk = 0; kk < 2; ++kk) {
        s16x8 bk = *(const s16x8*)(kbase + (size_t)(ni * 16 + fr) * 1536 + kk * 32 + fg * 8);
        sacc[ni] = __builtin_amdgcn_mfma_f32_16x16x32_bf16(aq[kk], bk, sacc[ni], 0, 0, 0);
      }
    }
    // ---- softmax over keys (rows in 16-lane groups) ----
    #pragma unroll
    for (int rr = 0; rr < 4; ++rr) {
      float mx = -1e30f;
      #pragma unroll
      for (int ni = 0; ni < 16; ++ni) mx = fmaxf(mx, sacc[ni][rr]);
      #pragma unroll
      for (int off = 1; off <= 8; off <<= 1) mx = fmaxf(mx, __shfl_xor(mx, off));
      float sum = 0.0f;
      #pragma unroll
      for (int ni = 0; ni < 16; ++ni) {
        float e = __expf((sacc[ni][rr] - mx) * 0.125f);
        sacc[ni][rr] = e; sum += e;
      }
      #pragma unroll
      for (int off = 1; off <= 8; off <<= 1) sum += __shfl_xor(sum, off);
      float inv = 1.0f / sum;
      #pragma unroll
      for (int ni = 0; ni < 16; ++ni) sacc[ni][rr] *= inv;
    }
    // ---- P: C-layout -> A-layout via swizzled per-wave LDS ----
    #pragma unroll
    for (int ni = 0; ni < 16; ++ni)
      #pragma unroll
      for (int rr = 0; rr < 4; ++rr) {
        int q = fg * 4 + rr;
        int c = ni * 2 + (fr >> 3);
        Pl[w][q * 256 + ((c ^ (q & 7)) << 3) + (fr & 7)] = f2b(sacc[ni][rr]);
      }
    // ---- O = P V (16 x 64), both operands from LDS ----
    f32x4 oacc[4] = {};
    #pragma unroll
    for (int kk = 0; kk < 8; ++kk) {
      int c = kk * 4 + fg;
      s16x8 ap = *(const s16x8*)&Pl[w][fr * 256 + ((c ^ (fr & 7)) << 3)];
      #pragma unroll
      for (int ni = 0; ni < 4; ++ni) {
        int d = ni * 16 + fr;
        s16x8 bv = *(const s16x8*)&Vt[d * 256 + ((c ^ (fr & 7)) << 3)];
        oacc[ni] = __builtin_amdgcn_mfma_f32_16x16x32_bf16(ap, bv, oacc[ni], 0, 0, 0);
      }
    }
    #pragma unroll
    for (int ni = 0; ni < 4; ++ni)
      #pragma unroll
      for (int rr = 0; rr < 4; ++rr) {
        int row = bb * 256 + q0 + fg * 4 + rr;
        int k = hh * 64 + ni * 16 + fr;
        obuf[tiled_off(row, k, 16)] = f2b(oacc[ni][rr]);
      }
  }
}

extern "C" void kernel_launch(void* const* d_in, const int* in_sizes, int n_in,
                              void* d_out, int out_size, void* d_ws, size_t ws_size,
                              hipStream_t stream) {
  const int*   x      = (const int*)  d_in[0];
  const float* emb    = (const float*)d_in[1];
  const float* qkv_w  = (const float*)d_in[2];
  const float* qkv_b  = (const float*)d_in[3];
  const float* out_w  = (const float*)d_in[4];
  const float* out_b  = (const float*)d_in[5];
  const float* ln1_s  = (const float*)d_in[6];
  const float* ln1_b  = (const float*)d_in[7];
  const float* ln2_s  = (const float*)d_in[8];
  const float* ln2_b  = (const float*)d_in[9];
  const float* ff1_w  = (const float*)d_in[10];
  const float* ff1_b  = (const float*)d_in[11];
  const float* ff2_w  = (const float*)d_in[12];
  const float* ff2_b  = (const float*)d_in[13];
  const float* fn_s   = (const float*)d_in[14];
  const float* fn_b   = (const float*)d_in[15];
  const float* head_w = (const float*)d_in[16];
  float* out = (float*)d_out;

  char* p = (char*)d_ws;
  float* h = (float*)p;                      p += (size_t)NTOK * D_ * 4;
  unsigned short* x2b = (unsigned short*)p;  p += (size_t)NTOK * D_ * 2;
  unsigned short* qkvb = (unsigned short*)p; p += (size_t)NTOK * 3 * D_ * 2;
  unsigned short* obuf = (unsigned short*)p; p += (size_t)NTOK * D_ * 2;
  unsigned short* wt_qkv = (unsigned short*)p; p += (size_t)L_ * D_ * 3 * D_ * 2;
  unsigned short* wt_out = (unsigned short*)p; p += (size_t)L_ * D_ * D_ * 2;
  unsigned short* wt_ff1 = (unsigned short*)p; p += (size_t)L_ * D_ * FF_ * 2;
  unsigned short* wt_ff2 = (unsigned short*)p; p += (size_t)FF_ * D_ * L_ * 2;
  unsigned short* wth = (unsigned short*)p;    p += (size_t)NLOC_ * D_ * 2;
  unsigned short* ffmid = qkvb;  // alias: qkvb(48MB)+obuf(16MB) = 64MB, dead during FF

  embed_kernel<<<NTOK, 256, 0, stream>>>(x, emb, h);
  wconv_kernel<<<dim3(3 * D_ / 128, D_ / 32, L_), 256, 0, stream>>>(
      qkv_w, wt_qkv, 3 * D_, D_ / 32, (long)D_ * 3 * D_, (long)D_ * 3 * D_);
  wconv_kernel<<<dim3(D_ / 128, D_ / 32, L_), 256, 0, stream>>>(
      out_w, wt_out, D_, D_ / 32, (long)D_ * D_, (long)D_ * D_);
  wconv_kernel<<<dim3(FF_ / 128, D_ / 32, L_), 256, 0, stream>>>(
      ff1_w, wt_ff1, FF_, D_ / 32, (long)D_ * FF_, (long)D_ * FF_);
  wconv_kernel<<<dim3(D_ / 128, FF_ / 32, L_), 256, 0, stream>>>(
      ff2_w, wt_ff2, D_, FF_ / 32, (long)FF_ * D_, (long)FF_ * D_);
  wconv_kernel<<<dim3(NLOC_ / 128, D_ / 32, 1), 256, 0, stream>>>(
      head_w, wth, V_, D_ / 32, 0, 0);

  for (int l = 0; l < L_; ++l) {
    ln_kernel<true><<<NTOK / 4, 256, 0, stream>>>(h, x2b, ln1_s + l * D_, ln1_b + l * D_);
    // qkv: A=x2b tiled (Kb=16), out=qkvb linear bf16
    mfma_gemm<true, false, false, true, false><<<dim3(3 * D_ / 128, NTOK / 128), 256, 0, stream>>>(
        x2b, 16, wt_qkv + (size_t)l * D_ * 3 * D_, qkv_b + (size_t)l * 3 * D_, nullptr, qkvb,
        NTOK, 3 * D_, D_, 3 * D_, 0);
    attn_mfma<<<B_ * H_, 256, 0, stream>>>(qkvb, obuf);
    // out-proj: A=obuf tiled (Kb=16), fp32 residual into h
    mfma_gemm<true, false, true, false, false><<<dim3(D_ / 128, NTOK / 128), 256, 0, stream>>>(
        obuf, 16, wt_out + (size_t)l * D_ * D_, out_b + (size_t)l * D_, h, nullptr,
        NTOK, D_, D_, D_, 0);
    ln_kernel<true><<<NTOK / 4, 256, 0, stream>>>(h, x2b, ln2_s + l * D_, ln2_b + l * D_);
    // ff1: A=x2b tiled (Kb=16), out=ffmid TILED bf16 (consumer Kb=64)
    mfma_gemm<true, true, false, true, true><<<dim3(FF_ / 128, NTOK / 128), 256, 0, stream>>>(
        x2b, 16, wt_ff1 + (size_t)l * D_ * FF_, ff1_b + (size_t)l * FF_, nullptr, ffmid,
        NTOK, FF_, D_, FF_, 64);
    // ff2: A=ffmid tiled (Kb=64), fp32 residual into h
    mfma_gemm<true, false, true, false, false><<<dim3(D_ / 128, NTOK / 128), 256, 0, stream>>>(
        ffmid, 64, wt_ff2 + (size_t)l * FF_ * D_, ff2_b + (size_t)l * D_, h, nullptr,
        NTOK, D_, FF_, D_, 0);
  }
  ln_kernel<false><<<NTOK / 4, 256, 0, stream>>>(h, x2b, fn_s, fn_b);
  head_gemm<<<dim3(NLOC_ / 128, 1), 256, 0, stream>>>(
      x2b + (size_t)(S_ - 1) * D_, (long)S_ * D_, wth, out, B_, NLOC_, D_, NLOC_);
}